// Round 6
// baseline (286.041 us; speedup 1.0000x reference)
//
#include <hip/hip_runtime.h>

// AirFitMultiHeadDNN — R6: decoupled threads.
// R5 post-mortem: halving FMAs left dur unchanged (110us) -> not
// throughput-bound. The 5-wave/64-item block couples waves through two
// barriers per chunk + a 5-way switch (5 code replicas, per-case s_load
// streams). R6 removes ALL coupling: thread = item, group loop unrolled,
// per group one int4 + three float4 loaded and consumed immediately
// (16 live values — the allocator-friendly pattern R4 validated), heads
// via R5's folded tables:
//   M[h] = Wf @ W1[h][3:8,:]             (SGPR path, compile-time idx)
//   T[h][idx][o]                          (LDS, 13 rows/head, b128 reads)
// No switch, no partial-sum LDS, no barrier after the one-time T stage.
// 2048 blocks x 256 thr = 8 waves/SIMD; VGPR capped 64, LDS 12.5KB ->
// 8 blocks/CU.

#define HH   20
#define NEX  13
#define TST  12                 // T row stride in floats
#define WS_M 0
#define WS_T 640

__device__ __forceinline__ float softplus_fast(float x) {
    return fmaxf(x, 0.0f) + __logf(1.0f + __expf(-fabsf(x)));
}

// ---------------- setup: fold weights into M and T ----------------
__global__ void airfit_setup(const float* __restrict__ emb,
                             const float* __restrict__ Wf,
                             const float* __restrict__ bf,
                             const float* __restrict__ W1,
                             const float* __restrict__ b1,
                             float* __restrict__ ws)
{
    int t = blockIdx.x * 256 + threadIdx.x;
    if (t < HH * 3 * 10) {                       // M[h][c][o]
        int h = t / 30, c = (t / 10) % 3, o = t % 10;
        float a = 0.0f;
        for (int q = 0; q < 5; ++q)
            a += Wf[c * 5 + q] * W1[(h * 8 + 3 + q) * 10 + o];
        ws[WS_M + (h * 3 + c) * 10 + o] = a;
    }
    if (t < HH * NEX * 10) {                     // T[h][idx][o]
        int h = t / (NEX * 10), idx = (t / 10) % NEX, o = t % 10;
        float a = b1[h * 10 + o];
        for (int i = 0; i < 3; ++i)
            a += emb[idx * 3 + i] * W1[(h * 8 + i) * 10 + o];
        for (int q = 0; q < 5; ++q)
            a += bf[q] * W1[(h * 8 + 3 + q) * 10 + o];
        ws[WS_T + (h * NEX + idx) * TST + o] = a;
    }
}

// ---------------- main ----------------
__global__ __launch_bounds__(256, 8) void airfit_kernel(
    const int*   __restrict__ e,   const float* __restrict__ f,
    const float* __restrict__ ws,  const float* __restrict__ W2,
    const float* __restrict__ b2,  const float* __restrict__ Wo,
    const float* __restrict__ bo,  float* __restrict__ out, int B)
{
    __shared__ float s_T[HH * NEX * TST];        // 3120 floats = 12.5 KB

    for (int t = threadIdx.x; t < HH * NEX * TST; t += 256)
        s_T[t] = ws[WS_T + t];
    __syncthreads();                             // only barrier in the kernel

    int item = blockIdx.x * 256 + threadIdx.x;
    if (item >= B) return;

    const int4*   ep = reinterpret_cast<const int4*>(e + (size_t)item * HH);
    const float4* fp = reinterpret_cast<const float4*>(f + (size_t)item * (HH * 3));
    const float* M = ws + WS_M;

    float acc = bo[0];

#pragma unroll
    for (int g = 0; g < 5; ++g) {
        // this group's inputs: 4 indices + 12 features, consumed immediately
        int4   iv = ep[g];
        float4 fa = fp[3 * g + 0];
        float4 fb = fp[3 * g + 1];
        float4 fc = fp[3 * g + 2];
        int   ii[4]  = { iv.x, iv.y, iv.z, iv.w };
        float ff[12] = { fa.x, fa.y, fa.z, fa.w,
                         fb.x, fb.y, fb.z, fb.w,
                         fc.x, fc.y, fc.z, fc.w };

#pragma unroll
        for (int t = 0; t < 4; ++t) {
            const int h = 4 * g + t;             // compile-time constant
            const float* Trow = s_T + (h * NEX + ii[t]) * TST;
            float4 t0 = *reinterpret_cast<const float4*>(Trow);      // o0..3
            float4 t1 = *reinterpret_cast<const float4*>(Trow + 4);  // o4..7
            float2 t2 = *reinterpret_cast<const float2*>(Trow + 8);  // o8..9
            float pre[10] = { t0.x, t0.y, t0.z, t0.w,
                              t1.x, t1.y, t1.z, t1.w, t2.x, t2.y };

            float g0 = ff[3 * t + 0], g1 = ff[3 * t + 1], g2 = ff[3 * t + 2];
            float hacc = b2[h];
#pragma unroll
            for (int o = 0; o < 10; ++o) {
                float a = pre[o];
                a = fmaf(g0, M[(h * 3 + 0) * 10 + o], a);
                a = fmaf(g1, M[(h * 3 + 1) * 10 + o], a);
                a = fmaf(g2, M[(h * 3 + 2) * 10 + o], a);
                a = fmaxf(a, 0.01f * a);         // leaky_relu
                hacc = fmaf(a, W2[h * 10 + o], hacc);
            }
            acc = fmaf(softplus_fast(hacc), Wo[h], acc);
        }
    }

    out[item] = acc;
}

extern "C" void kernel_launch(void* const* d_in, const int* in_sizes, int n_in,
                              void* d_out, int out_size, void* d_ws, size_t ws_size,
                              hipStream_t stream) {
    const int*   e   = (const int*)  d_in[0];
    const float* f   = (const float*)d_in[1];
    const float* emb = (const float*)d_in[2];
    const float* Wf  = (const float*)d_in[3];
    const float* bf  = (const float*)d_in[4];
    const float* W1  = (const float*)d_in[5];
    const float* b1  = (const float*)d_in[6];
    const float* W2  = (const float*)d_in[7];
    const float* b2  = (const float*)d_in[8];
    const float* Wo  = (const float*)d_in[9];
    const float* bo  = (const float*)d_in[10];
    float* out = (float*)d_out;
    float* ws  = (float*)d_ws;

    int B = in_sizes[0] / HH;                    // e is (B, 20)

    airfit_setup<<<11, 256, 0, stream>>>(emb, Wf, bf, W1, b1, ws);

    int blocks = (B + 255) / 256;
    airfit_kernel<<<blocks, 256, 0, stream>>>(e, f, ws, W2, b2, Wo, bo, out, B);
}

// Round 7
// 274.002 us; speedup vs baseline: 1.0439x; 1.0439x over previous
//
#include <hip/hip_runtime.h>

// AirFitMultiHeadDNN — R7: coalesced LDS staging + R6's lean compute.
// R6 post-mortem: VALU only 18% busy (lean!) but FETCH 377MB = 2.2x ideal,
// dur == FETCH/3.2TB/s -> pure HBM-overfetch-bound. Thread-per-item spreads
// 240B-strided loads over ~2000cyc; lines evicted between touches.
// R7: each 256-item block stages inputs ONCE with lane-contiguous loads:
//   f: 15 float4 loads/thread -> LDS SoA s_f4[15][257] (pad 257 =>
//      compute reads s_f4[c][tid] are consecutive-lane b128, conflict-free)
//   e: 5 int4 loads/thread, packed 4 idx/u32 -> s_ep[item*5+g]
//      (compute reads stride 5 words, gcd(5,32)=1, conflict-free)
//   T (R5 fold): 12.5KB -> LDS
// One barrier, then fully decoupled per-thread compute (R6 body):
//   h1 = leaky(T[h][idx] + f·M[h]); s = softplus(h1·W2+b2); out = s·Wo+bo
// M/W2/b2/Wo via compile-time-index global loads -> s_load/SGPR path.
// LDS = 79.3KB -> 2 blocks/CU, 8 waves/CU (LDS-capped on purpose).

#define HH   20
#define NEX  13
#define TST  12
#define WS_M 0
#define WS_T 640

__device__ __forceinline__ float softplus_fast(float x) {
    return fmaxf(x, 0.0f) + __logf(1.0f + __expf(-fabsf(x)));
}

// ---------------- setup: fold weights into M and T ----------------
__global__ void airfit_setup(const float* __restrict__ emb,
                             const float* __restrict__ Wf,
                             const float* __restrict__ bf,
                             const float* __restrict__ W1,
                             const float* __restrict__ b1,
                             float* __restrict__ ws)
{
    int t = blockIdx.x * 256 + threadIdx.x;
    if (t < HH * 3 * 10) {                       // M[h][c][o]
        int h = t / 30, c = (t / 10) % 3, o = t % 10;
        float a = 0.0f;
        for (int q = 0; q < 5; ++q)
            a += Wf[c * 5 + q] * W1[(h * 8 + 3 + q) * 10 + o];
        ws[WS_M + (h * 3 + c) * 10 + o] = a;
    }
    if (t < HH * NEX * 10) {                     // T[h][idx][o]
        int h = t / (NEX * 10), idx = (t / 10) % NEX, o = t % 10;
        float a = b1[h * 10 + o];
        for (int i = 0; i < 3; ++i)
            a += emb[idx * 3 + i] * W1[(h * 8 + i) * 10 + o];
        for (int q = 0; q < 5; ++q)
            a += bf[q] * W1[(h * 8 + 3 + q) * 10 + o];
        ws[WS_T + (h * NEX + idx) * TST + o] = a;
    }
}

// ---------------- main ----------------
__global__ __launch_bounds__(256, 2) void airfit_kernel(
    const int*   __restrict__ e,   const float* __restrict__ f,
    const float* __restrict__ ws,  const float* __restrict__ W2,
    const float* __restrict__ b2,  const float* __restrict__ Wo,
    const float* __restrict__ bo,  float* __restrict__ out, int B)
{
    __shared__ float4       s_f4[15][257];       // 61,680 B (pad 257)
    __shared__ unsigned int s_ep[256 * 5];       //  5,120 B
    __shared__ float        s_T[HH * NEX * TST]; // 12,480 B   => 79.3 KB

    const int tid  = threadIdx.x;
    const int base = blockIdx.x * 256;
    const int nIt  = min(256, B - base);         // full blocks when B%256==0

    // ---- stage T (ws is L2-hot after setup) ----
    for (int t = tid; t < HH * NEX * TST; t += 256)
        s_T[t] = ws[WS_T + t];

    // ---- stage f: lane-contiguous float4 loads -> SoA LDS ----
    {
        const float4* fg = reinterpret_cast<const float4*>(f) + (size_t)base * 15;
        const int total4 = nIt * 15;
#pragma unroll
        for (int k = 0; k < 15; ++k) {
            int idx = tid + 256 * k;             // 0..3839
            if (idx < total4) {
                float4 v = fg[idx];
                int item = idx / 15, c4 = idx - item * 15;
                s_f4[c4][item] = v;
            }
        }
    }

    // ---- stage e: lane-contiguous int4 loads, pack 4 idx per u32 ----
    {
        const int4* eg = reinterpret_cast<const int4*>(e) + (size_t)base * 5;
        const int total4 = nIt * 5;
#pragma unroll
        for (int k = 0; k < 5; ++k) {
            int idx = tid + 256 * k;             // 0..1279
            if (idx < total4) {
                int4 iv = eg[idx];
                s_ep[idx] = (unsigned)iv.x | ((unsigned)iv.y << 8) |
                            ((unsigned)iv.z << 16) | ((unsigned)iv.w << 24);
            }
        }
    }

    __syncthreads();                             // only barrier

    if (tid >= nIt) return;
    const float* M = ws + WS_M;

    float acc = bo[0];

#pragma unroll
    for (int g = 0; g < 5; ++g) {
        unsigned ep = s_ep[tid * 5 + g];         // stride 5 -> conflict-free
        float4 fA = s_f4[3 * g + 0][tid];        // consecutive-lane b128
        float4 fB = s_f4[3 * g + 1][tid];
        float4 fC = s_f4[3 * g + 2][tid];
        float ff[12] = { fA.x, fA.y, fA.z, fA.w,
                         fB.x, fB.y, fB.z, fB.w,
                         fC.x, fC.y, fC.z, fC.w };

#pragma unroll
        for (int t = 0; t < 4; ++t) {
            const int h = 4 * g + t;             // compile-time constant
            int idx = (ep >> (8 * t)) & 0xff;

            const float* Trow = s_T + (h * NEX + idx) * TST;
            float4 t0 = *reinterpret_cast<const float4*>(Trow);
            float4 t1 = *reinterpret_cast<const float4*>(Trow + 4);
            float2 t2 = *reinterpret_cast<const float2*>(Trow + 8);
            float pre[10] = { t0.x, t0.y, t0.z, t0.w,
                              t1.x, t1.y, t1.z, t1.w, t2.x, t2.y };

            float g0 = ff[3 * t + 0], g1 = ff[3 * t + 1], g2 = ff[3 * t + 2];
            float hacc = b2[h];
#pragma unroll
            for (int o = 0; o < 10; ++o) {
                float a = pre[o];
                a = fmaf(g0, M[(h * 3 + 0) * 10 + o], a);
                a = fmaf(g1, M[(h * 3 + 1) * 10 + o], a);
                a = fmaf(g2, M[(h * 3 + 2) * 10 + o], a);
                a = fmaxf(a, 0.01f * a);         // leaky_relu
                hacc = fmaf(a, W2[h * 10 + o], hacc);
            }
            acc = fmaf(softplus_fast(hacc), Wo[h], acc);
        }
    }

    out[base + tid] = acc;
}

extern "C" void kernel_launch(void* const* d_in, const int* in_sizes, int n_in,
                              void* d_out, int out_size, void* d_ws, size_t ws_size,
                              hipStream_t stream) {
    const int*   e   = (const int*)  d_in[0];
    const float* f   = (const float*)d_in[1];
    const float* emb = (const float*)d_in[2];
    const float* Wf  = (const float*)d_in[3];
    const float* bf  = (const float*)d_in[4];
    const float* W1  = (const float*)d_in[5];
    const float* b1  = (const float*)d_in[6];
    const float* W2  = (const float*)d_in[7];
    const float* b2  = (const float*)d_in[8];
    const float* Wo  = (const float*)d_in[9];
    const float* bo  = (const float*)d_in[10];
    float* out = (float*)d_out;
    float* ws  = (float*)d_ws;

    int B = in_sizes[0] / HH;                    // e is (B, 20)

    airfit_setup<<<11, 256, 0, stream>>>(emb, Wf, bf, W1, b1, ws);

    int blocks = (B + 255) / 256;
    airfit_kernel<<<blocks, 256, 0, stream>>>(e, f, ws, W2, b2, Wo, bo, out, B);
}